// Round 8
// baseline (391.744 us; speedup 1.0000x reference)
//
#include <hip/hip_runtime.h>
#include <math.h>

// ---------------------------------------------------------------------------
// Fastformer encoder layer — Round 8: fully barrier-free GEMMs, both
// operands pre-swizzled to MFMA fragment-linear layout.
//
// R7 post-mortem: 898 TF = m97-structure plateau; vmcnt(0)+s_barrier drain
// of global_load_lds exposes HBM latency every K-stage. R8 removes LDS and
// barriers from the GEMM K-loop entirely:
//  * Weights (R6, validated) AND activations are stored fragment-linear:
//    chunk (ntile, kt) of 64 lanes x 16B; a fragment load is base+lane*16B.
//  * GEMM K-loop: A,B direct global->reg, ping-pong dbuf, no sync at all.
//  * Producers write frag-linear: ln_fragout (16-row blocks, 16-lane-group
//    reductions), vscale_frag, lin1 epilogue (2nd LDS exchange).
//  * kv16 stays row-major for attn; vscale converts v -> frag-linear vq.
// ws: h16@0(16M) | kv16/act16@16M(32M overlay) | vq@48M(16M) |
//     swizzled weights@64M(18M) | gk@82M | attn partials@83M
// ---------------------------------------------------------------------------

#define DM     1024
#define FFH    2048
#define M_TOT  8192

typedef _Float16 f16x8 __attribute__((ext_vector_type(8)));
typedef float    f32x4 __attribute__((ext_vector_type(4)));

__device__ __forceinline__ unsigned short f2h(float x) {
    union { _Float16 h; unsigned short u; } c;
    c.h = (_Float16)x;
    return c.u;
}
__device__ __forceinline__ float h2f(unsigned short u) {
    union { unsigned short u; _Float16 h; } c;
    c.u = u;
    return (float)c.h;
}

// ---------------------------------------------------------------------------
// weight cast fp32 -> fp16 fragment-linear (validated R6/R7):
// chunk i = (ntile*KT + kt)*64 + lane ; holds
// W[nt*16 + (lane&15)][kt*32 + (lane>>4)*8 .. +8].
// ---------------------------------------------------------------------------
__global__ __launch_bounds__(256) void wcast_sw(
    const float* __restrict__ s0, const float* __restrict__ s1,
    const float* __restrict__ s2, const float* __restrict__ s3,
    unsigned short* __restrict__ d0, unsigned short* __restrict__ d1,
    unsigned short* __restrict__ d2, unsigned short* __restrict__ d3)
{
    int i = blockIdx.x * 256 + threadIdx.x;
    const float* s; unsigned short* d; int ks;
    if      (i < 262144) {               s = s0; d = d0; ks = 5; }
    else if (i < 393216) { i -= 262144;  s = s1; d = d1; ks = 5; }
    else if (i < 917504) { i -= 393216;  s = s2; d = d2; ks = 5; }
    else                 { i -= 917504;  s = s3; d = d3; ks = 6; }
    const int lane = i & 63, tile = i >> 6;
    const int kt = tile & ((1 << ks) - 1), nt = tile >> ks;
    const int fr = lane & 15, qq = lane >> 4;
    const int K = 32 << ks;
    const float* src = s + (size_t)(nt * 16 + fr) * K + kt * 32 + qq * 8;
    const float4 v0 = ((const float4*)src)[0];
    const float4 v1 = ((const float4*)src)[1];
    ushort4 h0, h1;
    h0.x = f2h(v0.x); h0.y = f2h(v0.y); h0.z = f2h(v0.z); h0.w = f2h(v0.w);
    h1.x = f2h(v1.x); h1.y = f2h(v1.y); h1.z = f2h(v1.z); h1.w = f2h(v1.w);
    unsigned short* dst = d + (size_t)i * 8;
    *(ushort4*)dst       = h0;
    *(ushort4*)(dst + 4) = h1;
}

// ---------------------------------------------------------------------------
// LayerNorm -> fp16 FRAGMENT-LINEAR output (KT=32).
// Block = 16 rows (one m-tile). Thread u: fr=u&15 (row), ci=u>>4 (col chunk
// of 64). Reads x[row][ci*64..+63] (L1 absorbs the 4KB row stride), stats
// via shfl_xor(16,32) + tiny LDS, writes 8 coalesced 16B frag stores.
// ---------------------------------------------------------------------------
__global__ __launch_bounds__(256) void ln_fragout(
    const float* __restrict__ x, const float* __restrict__ g,
    const float* __restrict__ b, unsigned short* __restrict__ y)
{
    const int m0 = blockIdx.x * 16;
    const int t  = threadIdx.x;
    const int fr = t & 15, ci = t >> 4, w = t >> 6;

    const float* src = x + (size_t)(m0 + fr) * DM + ci * 64;
    float4 xv[16];
    float s = 0.f, ss = 0.f;
    #pragma unroll
    for (int j = 0; j < 16; ++j) {
        xv[j] = *(const float4*)(src + j * 4);
        s  += xv[j].x + xv[j].y + xv[j].z + xv[j].w;
        ss += xv[j].x * xv[j].x + xv[j].y * xv[j].y
            + xv[j].z * xv[j].z + xv[j].w * xv[j].w;
    }
    // sum the 4 ci's in this wave (lanes fr, fr+16, fr+32, fr+48)
    s  += __shfl_xor(s, 16);  s  += __shfl_xor(s, 32);
    ss += __shfl_xor(ss, 16); ss += __shfl_xor(ss, 32);
    __shared__ float sm[4][16][2];
    if ((t & 63) < 16) { sm[w][fr][0] = s; sm[w][fr][1] = ss; }
    __syncthreads();
    s  = sm[0][fr][0] + sm[1][fr][0] + sm[2][fr][0] + sm[3][fr][0];
    ss = sm[0][fr][1] + sm[1][fr][1] + sm[2][fr][1] + sm[3][fr][1];

    const float mu  = s * (1.0f / DM);
    const float var = ss * (1.0f / DM) - mu * mu;
    const float r   = rsqrtf(var + 1e-5f);

    // frag-linear stores: octet o -> kt = ci*2+(o>>2), q = o&3
    unsigned short* dst = y + ((size_t)(m0 >> 4) * 32) * 512;
    #pragma unroll
    for (int o = 0; o < 8; ++o) {
        const float4 g0 = *(const float4*)(g + ci * 64 + o * 8);
        const float4 g1 = *(const float4*)(g + ci * 64 + o * 8 + 4);
        const float4 b0 = *(const float4*)(b + ci * 64 + o * 8);
        const float4 b1 = *(const float4*)(b + ci * 64 + o * 8 + 4);
        const float4 v0 = xv[o * 2], v1 = xv[o * 2 + 1];
        union { ushort4 u4[2]; f16x8 v; } pk;
        pk.u4[0].x = f2h((v0.x - mu) * r * g0.x + b0.x);
        pk.u4[0].y = f2h((v0.y - mu) * r * g0.y + b0.y);
        pk.u4[0].z = f2h((v0.z - mu) * r * g0.z + b0.z);
        pk.u4[0].w = f2h((v0.w - mu) * r * g0.w + b0.w);
        pk.u4[1].x = f2h((v1.x - mu) * r * g1.x + b1.x);
        pk.u4[1].y = f2h((v1.y - mu) * r * g1.y + b1.y);
        pk.u4[1].z = f2h((v1.z - mu) * r * g1.z + b1.z);
        pk.u4[1].w = f2h((v1.w - mu) * r * g1.w + b1.w);
        const int kt = ci * 2 + (o >> 2), q = o & 3;
        *(f16x8*)(dst + (size_t)kt * 512 + (q * 16 + fr) * 8) = pk.v;
    }
}

// ---------------------------------------------------------------------------
// attention partial pass + merge (verified R4-R7), kv16 row-major.
// ---------------------------------------------------------------------------
__global__ __launch_bounds__(256) void attn_part(
    const unsigned short* __restrict__ kv, const float* __restrict__ kw,
    float* __restrict__ pm, float* __restrict__ pl, float* __restrict__ ps)
{
    const int blk = blockIdx.x;
    const int bh = blk >> 2, qt = blk & 3;
    const int b = bh >> 4, h = bh & 15;
    const int t = threadIdx.x, e = t & 63, w = t >> 6;
    const int nbase = qt * 256 + w * 64;
    const unsigned short* kp =
        kv + (size_t)b * 1024 * 2048 + (size_t)nbase * 2048 + h * 64 + e;
    const float* kwr = kw + h * 1024 + nbase;

    float m = -1e30f, l = 0.f, s = 0.f;
    #pragma unroll 4
    for (int i = 0; i < 64; ++i) {
        const float kval = h2f(kp[(size_t)i * 2048]);
        const float x    = kval * kwr[i] * 0.125f;
        const float nm   = fmaxf(m, x);
        const float c    = __expf(m - nm);
        const float ex   = __expf(x - nm);
        l = l * c + ex;
        s = s * c + ex * kval;
        m = nm;
    }
    __shared__ float sm[3][256];
    sm[0][t] = m; sm[1][t] = l; sm[2][t] = s;
    __syncthreads();
    if (t < 64) {
        #pragma unroll
        for (int ww = 1; ww < 4; ++ww) {
            const float m2 = sm[0][ww * 64 + e];
            const float l2 = sm[1][ww * 64 + e];
            const float s2 = sm[2][ww * 64 + e];
            const float nm = fmaxf(m, m2);
            const float c1 = __expf(m - nm);
            const float c2 = __expf(m2 - nm);
            l = l * c1 + l2 * c2;
            s = s * c1 + s2 * c2;
            m = nm;
        }
        const int o = blk * 64 + e;
        pm[o] = m; pl[o] = l; ps[o] = s;
    }
}

__global__ __launch_bounds__(64) void attn_merge(
    const float* __restrict__ pm, const float* __restrict__ pl,
    const float* __restrict__ ps, float* __restrict__ gk)
{
    const int bh = blockIdx.x, e = threadIdx.x;
    const int b = bh >> 4, h = bh & 15;
    int o = bh * 4 * 64 + e;
    float m = pm[o], l = pl[o], s = ps[o];
    #pragma unroll
    for (int qt = 1; qt < 4; ++qt) {
        o += 64;
        const float m2 = pm[o], l2 = pl[o], s2 = ps[o];
        const float nm = fmaxf(m, m2);
        const float c1 = __expf(m - nm);
        const float c2 = __expf(m2 - nm);
        l = l * c1 + l2 * c2;
        s = s * c1 + s2 * c2;
        m = nm;
    }
    gk[(size_t)b * DM + h * 64 + e] = s / l;
}

// ---------------------------------------------------------------------------
// v-scale -> FRAGMENT-LINEAR vq (KT=32). Same 16-row-block thread map as
// ln_fragout; reads row-major v half of kv16 (L1 absorbs stride), writes
// coalesced 16B frag stores.
// ---------------------------------------------------------------------------
__global__ __launch_bounds__(256) void vscale_frag(
    const unsigned short* __restrict__ kv, const float* __restrict__ gk,
    unsigned short* __restrict__ vq)
{
    const int m0 = blockIdx.x * 16;
    const int t  = threadIdx.x;
    const int fr = t & 15, ci = t >> 4;
    const int b  = m0 >> 10;

    const unsigned short* src = kv + (size_t)(m0 + fr) * 2048 + 1024 + ci * 64;
    const float* gkr = gk + (size_t)b * DM + ci * 64;
    unsigned short* dst = vq + ((size_t)(m0 >> 4) * 32) * 512;

    #pragma unroll
    for (int o = 0; o < 8; ++o) {
        const ushort4 v0 = *(const ushort4*)(src + o * 8);
        const ushort4 v1 = *(const ushort4*)(src + o * 8 + 4);
        const float4  g0 = *(const float4*)(gkr + o * 8);
        const float4  g1 = *(const float4*)(gkr + o * 8 + 4);
        union { ushort4 u4[2]; f16x8 v; } pk;
        pk.u4[0].x = f2h(h2f(v0.x) * g0.x);
        pk.u4[0].y = f2h(h2f(v0.y) * g0.y);
        pk.u4[0].z = f2h(h2f(v0.z) * g0.z);
        pk.u4[0].w = f2h(h2f(v0.w) * g0.w);
        pk.u4[1].x = f2h(h2f(v1.x) * g1.x);
        pk.u4[1].y = f2h(h2f(v1.y) * g1.y);
        pk.u4[1].z = f2h(h2f(v1.z) * g1.z);
        pk.u4[1].w = f2h(h2f(v1.w) * g1.w);
        const int kt = ci * 2 + (o >> 2), q = o & 3;
        *(f16x8*)(dst + (size_t)kt * 512 + (q * 16 + fr) * 8) = pk.v;
    }
}

// ---------------------------------------------------------------------------
// Barrier-free fp16 MFMA GEMM, BOTH operands fragment-linear.
// 256 thr = 4 waves (2x2), block tile 128 rows x 128 cols (LIN1ACT: 64 out
// cols, wn=0 a-half / wn=1 g-half). Wave 64x64, acc 64 AGPR. K-loop: zero
// LDS, zero barriers; A,B frag loads base+lane*16B, ping-pong dbuf ->
// compiler emits fine-grained vmcnt(N). OUTM: 0 fp16 row-major out,
// 2 fp32 row-major out + residual. LIN1ACT writes act16 FRAG-LINEAR via
// 16KB LDS double-exchange.
// ---------------------------------------------------------------------------
template <bool LIN1ACT, int OUTM>
__global__ __launch_bounds__(256, 3) void fgemm(
    const unsigned short* __restrict__ A,
    const unsigned short* __restrict__ Bsw,
    const float* __restrict__ bias,
    const float* __restrict__ residual,
    float* __restrict__ Cf, unsigned short* __restrict__ Cq,
    int K, int ldc)
{
    __shared__ __align__(16) unsigned short xch[8192];  // LIN1ACT only (16KB)

    const int t  = threadIdx.x;
    const int m0 = blockIdx.y * 128;
    const int n0 = blockIdx.x * (LIN1ACT ? 64 : 128);
    const int L  = t & 63, w = t >> 6;
    const int wm = w >> 1, wn = w & 1;
    const int fr = L & 15, q = L >> 4;
    const int KT = K >> 5;

    // fragment-linear chunk offsets (halves); + kt*512 per k-tile
    size_t aoff[4], boff[4];
    #pragma unroll
    for (int mi = 0; mi < 4; ++mi) {
        const int mt = (m0 + wm * 64 + mi * 16) >> 4;
        aoff[mi] = (size_t)mt * KT * 512 + L * 8;
    }
    const int bcol0 = LIN1ACT ? ((wn ? FFH : 0) + n0) : (n0 + wn * 64);
    #pragma unroll
    for (int ni = 0; ni < 4; ++ni)
        boff[ni] = (size_t)((bcol0 >> 4) + ni) * KT * 512 + L * 8;

    f32x4 acc[4][4];
    #pragma unroll
    for (int i = 0; i < 4; ++i)
        #pragma unroll
        for (int j = 0; j < 4; ++j) acc[i][j] = (f32x4){0.f, 0.f, 0.f, 0.f};

    f16x8 a0[4], b0[4], a1[4], b1[4];
    #pragma unroll
    for (int mi = 0; mi < 4; ++mi) a0[mi] = *(const f16x8*)(A + aoff[mi]);
    #pragma unroll
    for (int ni = 0; ni < 4; ++ni) b0[ni] = *(const f16x8*)(Bsw + boff[ni]);

    for (int k0 = 0; k0 < K; k0 += 64) {
        const int ktn = k0 >> 5;
        #pragma unroll
        for (int mi = 0; mi < 4; ++mi)
            a1[mi] = *(const f16x8*)(A + aoff[mi] + (ktn + 1) * 512);
        #pragma unroll
        for (int ni = 0; ni < 4; ++ni)
            b1[ni] = *(const f16x8*)(Bsw + boff[ni] + (ktn + 1) * 512);
        #pragma unroll
        for (int mi = 0; mi < 4; ++mi)
            #pragma unroll
            for (int ni = 0; ni < 4; ++ni)
                acc[mi][ni] = __builtin_amdgcn_mfma_f32_16x16x32_f16(
                    a0[mi], b0[ni], acc[mi][ni], 0, 0, 0);

        const int kt2 = (ktn + 2 < KT) ? ktn + 2 : 0;   // tail: benign re-read
        #pragma unroll
        for (int mi = 0; mi < 4; ++mi)
            a0[mi] = *(const f16x8*)(A + aoff[mi] + kt2 * 512);
        #pragma unroll
        for (int ni = 0; ni < 4; ++ni)
            b0[ni] = *(const f16x8*)(Bsw + boff[ni] + kt2 * 512);
        #pragma unroll
        for (int mi = 0; mi < 4; ++mi)
            #pragma unroll
            for (int ni = 0; ni < 4; ++ni)
                acc[mi][ni] = __builtin_amdgcn_mfma_f32_16x16x32_f16(
                    a1[mi], b1[ni], acc[mi][ni], 0, 0, 0);
    }

    if (!LIN1ACT) {
        float bc[4];
        #pragma unroll
        for (int ni = 0; ni < 4; ++ni)
            bc[ni] = bias[n0 + wn * 64 + ni * 16 + fr];
        #pragma unroll
        for (int mi = 0; mi < 4; ++mi)
            #pragma unroll
            for (int ni = 0; ni < 4; ++ni) {
                const int gcol = n0 + wn * 64 + ni * 16 + fr;
                #pragma unroll
                for (int r = 0; r < 4; ++r) {
                    const int grow = m0 + wm * 64 + mi * 16 + q * 4 + r;
                    float v = acc[mi][ni][r] + bc[ni];
                    if (OUTM == 2) {
                        v += residual[(size_t)grow * ldc + gcol];
                        Cf[(size_t)grow * ldc + gcol] = v;
                    } else {
                        Cq[(size_t)grow * ldc + gcol] = f2h(v);
                    }
                }
            }
    } else {
        // exchange 1: g-half -> xch
        if (wn == 1) {
            #pragma unroll
            for (int mi = 0; mi < 4; ++mi)
                #pragma unroll
                for (int ni = 0; ni < 4; ++ni) {
                    const int col = ni * 16 + fr;
                    const float bg = bias[FFH + n0 + col];
                    #pragma unroll
                    for (int r = 0; r < 4; ++r) {
                        const int row = wm * 64 + mi * 16 + q * 4 + r;
                        xch[row * 64 + col] =
                            f2h(fmaxf(acc[mi][ni][r] + bg, 0.f));
                    }
                }
        }
        __syncthreads();
        // exchange 2: a-half computes o, overwrites same slots (same thread)
        if (wn == 0) {
            #pragma unroll
            for (int mi = 0; mi < 4; ++mi)
                #pragma unroll
                for (int ni = 0; ni < 4; ++ni) {
                    const int col = ni * 16 + fr;
                    const float ba = bias[n0 + col];
                    #pragma unroll
                    for (int r = 0; r < 4; ++r) {
                        const int row = wm * 64 + mi * 16 + q * 4 + r;
                        const float a = acc[mi][ni][r] + ba;
                        xch[row * 64 + col] = f2h(a * h2f(xch[row * 64 + col]));
                    }
                }
        }
        __syncthreads();
        // cooperative frag-linear store: 16 chunks (8 mtiles x 2 kt)
        const int c  = t >> 4;            // 0..15: mt = c>>1, ktl = c&1
        const int mt = c >> 1, ktl = c & 1;
        unsigned short* gdst = Cq +
            ((size_t)((m0 >> 4) + mt) * 64 + (n0 >> 5) + ktl) * 512;
        #pragma unroll
        for (int k = 0; k < 4; ++k) {
            const int Lc  = (t & 15) * 4 + k;
            const int row = mt * 16 + (Lc & 15);
            const int col = ktl * 32 + (Lc >> 4) * 8;
            *(f16x8*)(gdst + Lc * 8) = *(const f16x8*)(xch + row * 64 + col);
        }
    }
}

// ---------------------------------------------------------------------------
extern "C" void kernel_launch(void* const* d_in, const int* in_sizes, int n_in,
                              void* d_out, int out_size, void* d_ws, size_t ws_size,
                              hipStream_t stream)
{
    const float* hidden = (const float*)d_in[0];
    const float* qkv_w  = (const float*)d_in[2];
    const float* qkv_b  = (const float*)d_in[3];
    const float* out_w  = (const float*)d_in[4];
    const float* out_b  = (const float*)d_in[5];
    const float* key_w  = (const float*)d_in[7];
    const float* n1g    = (const float*)d_in[8];
    const float* n1b    = (const float*)d_in[9];
    const float* n2g    = (const float*)d_in[10];
    const float* n2b    = (const float*)d_in[11];
    const float* l1w    = (const float*)d_in[12];
    const float* l1b    = (const float*)d_in[13];
    const float* l2w    = (const float*)d_in[14];
    const float* l2b    = (const float*)d_in[15];
    float* out = (float*)d_out;
    char*  wsb = (char*)d_ws;

    const size_t MB = 1u << 20;
    unsigned short* h16    = (unsigned short*)wsb;               // 16 MB
    unsigned short* kv16   = (unsigned short*)(wsb + 16 * MB);   // 32 MB
    unsigned short* act16  = (unsigned short*)(wsb + 16 * MB);   // overlay
    unsigned short* vq     = (unsigned short*)(wsb + 48 * MB);   // 16 MB
    unsigned short* wkv_sw = (unsigned short*)(wsb + 64 * MB);   // 4 MB
    unsigned short* wo_sw  = (unsigned short*)(wsb + 68 * MB);   // 2 MB
    unsigned short* l1_sw  = (unsigned short*)(wsb + 70 * MB);   // 8 MB
    unsigned short* l2_sw  = (unsigned short*)(wsb + 78 * MB);   // 4 MB
    float*          gk     = (float*)(wsb + 82 * MB);            // 32 KB
    float*          pm     = (float*)(wsb + 83 * MB);            // 128 KB
    float*          pl     = (float*)(wsb + 83 * MB + 131072);
    float*          ps     = (float*)(wsb + 83 * MB + 262144);

    // 0. weights -> fp16 fragment-linear
    wcast_sw<<<4608, 256, 0, stream>>>(
        qkv_w + (size_t)DM * DM, out_w, l1w, l2w,
        wkv_sw, wo_sw, l1_sw, l2_sw);

    // 1. h1 = LN1(hidden) -> frag-linear fp16
    ln_fragout<<<M_TOT / 16, 256, 0, stream>>>(hidden, n1g, n1b, h16);

    // 2. kv16 = fp16( h1 @ Wkv^T + b )  row-major (ldc 2048), 1024 blocks
    fgemm<false, 0><<<dim3(16, 64), 256, 0, stream>>>(
        h16, wkv_sw, qkv_b + DM, nullptr, nullptr, kv16, 1024, 2048);

    // 3. global_key (partial + merge)
    attn_part<<<512, 256, 0, stream>>>(kv16, key_w, pm, pl, ps);
    attn_merge<<<128, 64, 0, stream>>>(pm, pl, ps, gk);

    // 4. vq = fp16(v * gk) -> frag-linear
    vscale_frag<<<M_TOT / 16, 256, 0, stream>>>(kv16, gk, vq);

    // 5. hidden2 = hidden + vq @ out_w^T + out_b -> d_out, 512 blocks
    fgemm<false, 2><<<dim3(8, 64), 256, 0, stream>>>(
        vq, wo_sw, out_b, hidden, out, nullptr, 1024, 1024);

    // 6. h2 = LN2(hidden2) -> frag-linear fp16
    ln_fragout<<<M_TOT / 16, 256, 0, stream>>>(out, n2g, n2b, h16);

    // 7. act16 = fp16( (h2@W_a^T+b_a) * relu(h2@W_g^T+b_g) ) -> frag-linear
    fgemm<true, 0><<<dim3(32, 64), 256, 0, stream>>>(
        h16, l1_sw, l1b, nullptr, nullptr, act16, 1024, 0);

    // 8. out = hidden2 + act @ l2w^T + l2b (in-place residual), 512 blocks
    fgemm<false, 2><<<dim3(8, 64), 256, 0, stream>>>(
        act16, l2_sw, l2b, out, out, nullptr, 2048, 1024);
}

// Round 9
// 382.601 us; speedup vs baseline: 1.0239x; 1.0239x over previous
//
#include <hip/hip_runtime.h>
#include <math.h>

// ---------------------------------------------------------------------------
// Fastformer encoder layer — Round 9: R7 GEMM (proven) + 4 blocks/CU +
// chain-free attention.
//
// R8 post-mortem: dropping LDS-shared A doubled L2 traffic and 1-stage reg
// ping-pong can't cover L2 latency -> 31% MfmaUtil. REVERTED to R7's
// LDS-dbuf-A + swizzled-direct-B (898 TF lin1). Changes vs R7:
//  * fgemm __launch_bounds__(256,4): R7 used exactly 64 VGPR + 64 AGPR =
//    128 unified = the 4-waves/SIMD boundary -> 16 waves/CU co-residency.
//  * attn: |k*kw/8| <~ 0.3 -> softmax max-subtraction dropped; l,s are
//    plain parallel sums; single 128-block kernel, no partial/merge pass.
// ws: h16@0(16M) | kv16/act16@16M(32M overlay) | vq@48M(16M) |
//     swizzled weights@64M(18M) | gk@82M
// ---------------------------------------------------------------------------

#define DM     1024
#define FFH    2048
#define M_TOT  8192

typedef _Float16 f16x8 __attribute__((ext_vector_type(8)));
typedef float    f32x4 __attribute__((ext_vector_type(4)));

__device__ __forceinline__ void gl2lds16(const void* g, void* l) {
    __builtin_amdgcn_global_load_lds(
        (const __attribute__((address_space(1))) void*)g,
        (__attribute__((address_space(3))) void*)l, 16, 0, 0);
}
__device__ __forceinline__ unsigned short f2h(float x) {
    union { _Float16 h; unsigned short u; } c;
    c.h = (_Float16)x;
    return c.u;
}
__device__ __forceinline__ float h2f(unsigned short u) {
    union { unsigned short u; _Float16 h; } c;
    c.u = u;
    return (float)c.h;
}

// ---------------------------------------------------------------------------
// weight cast fp32 -> fp16 fragment-linear (validated R6/R7):
// chunk i = (ntile*KT + kt)*64 + lane ; holds
// W[nt*16 + (lane&15)][kt*32 + (lane>>4)*8 .. +8].
// ---------------------------------------------------------------------------
__global__ __launch_bounds__(256) void wcast_sw(
    const float* __restrict__ s0, const float* __restrict__ s1,
    const float* __restrict__ s2, const float* __restrict__ s3,
    unsigned short* __restrict__ d0, unsigned short* __restrict__ d1,
    unsigned short* __restrict__ d2, unsigned short* __restrict__ d3)
{
    int i = blockIdx.x * 256 + threadIdx.x;
    const float* s; unsigned short* d; int ks;
    if      (i < 262144) {               s = s0; d = d0; ks = 5; }
    else if (i < 393216) { i -= 262144;  s = s1; d = d1; ks = 5; }
    else if (i < 917504) { i -= 393216;  s = s2; d = d2; ks = 5; }
    else                 { i -= 917504;  s = s3; d = d3; ks = 6; }
    const int lane = i & 63, tile = i >> 6;
    const int kt = tile & ((1 << ks) - 1), nt = tile >> ks;
    const int fr = lane & 15, qq = lane >> 4;
    const int K = 32 << ks;
    const float* src = s + (size_t)(nt * 16 + fr) * K + kt * 32 + qq * 8;
    const float4 v0 = ((const float4*)src)[0];
    const float4 v1 = ((const float4*)src)[1];
    ushort4 h0, h1;
    h0.x = f2h(v0.x); h0.y = f2h(v0.y); h0.z = f2h(v0.z); h0.w = f2h(v0.w);
    h1.x = f2h(v1.x); h1.y = f2h(v1.y); h1.z = f2h(v1.z); h1.w = f2h(v1.w);
    unsigned short* dst = d + (size_t)i * 8;
    *(ushort4*)dst       = h0;
    *(ushort4*)(dst + 4) = h1;
}

// ---------------------------------------------------------------------------
// LayerNorm -> fp16 row-major (R7 version). One block/row, one f4/thread.
// ---------------------------------------------------------------------------
__global__ __launch_bounds__(256) void ln_f16(
    const float* __restrict__ x, const float* __restrict__ g,
    const float* __restrict__ b, unsigned short* __restrict__ y)
{
    const int row = blockIdx.x;
    const int t   = threadIdx.x;
    const float4 v = ((const float4*)(x + (size_t)row * DM))[t];

    float s  = v.x + v.y + v.z + v.w;
    float ss = v.x * v.x + v.y * v.y + v.z * v.z + v.w * v.w;
    #pragma unroll
    for (int off = 32; off > 0; off >>= 1) {
        s  += __shfl_xor(s, off);
        ss += __shfl_xor(ss, off);
    }
    __shared__ float sm[8];
    const int wave = t >> 6;
    if ((t & 63) == 0) { sm[wave * 2] = s; sm[wave * 2 + 1] = ss; }
    __syncthreads();
    s  = sm[0] + sm[2] + sm[4] + sm[6];
    ss = sm[1] + sm[3] + sm[5] + sm[7];

    const float mu  = s * (1.0f / DM);
    const float var = ss * (1.0f / DM) - mu * mu;
    const float r   = rsqrtf(var + 1e-5f);

    const float4 gv = ((const float4*)g)[t];
    const float4 bv = ((const float4*)b)[t];
    ushort4 o;
    o.x = f2h((v.x - mu) * r * gv.x + bv.x);
    o.y = f2h((v.y - mu) * r * gv.y + bv.y);
    o.z = f2h((v.z - mu) * r * gv.z + bv.z);
    o.w = f2h((v.w - mu) * r * gv.w + bv.w);
    ((ushort4*)(y + (size_t)row * DM))[t] = o;
}

// ---------------------------------------------------------------------------
// attention: gk[b,h,e] = softmax-weighted sum of k over n. |x|<~0.3 so no
// max subtraction needed: l = sum exp(x), s = sum exp(x)*k — parallel,
// reassociable sums (no serial online-softmax chain). 128 blocks (b,h),
// 4 waves x 256 n each, LDS cross-wave reduce.
// ---------------------------------------------------------------------------
__global__ __launch_bounds__(256) void attn_gk(
    const unsigned short* __restrict__ kv, const float* __restrict__ kw,
    float* __restrict__ gk)
{
    const int bh = blockIdx.x;
    const int b = bh >> 4, h = bh & 15;
    const int t = threadIdx.x, e = t & 63, w = t >> 6;
    const unsigned short* kp =
        kv + (size_t)b * 1024 * 2048 + (size_t)(w * 256) * 2048 + h * 64 + e;
    const float* kwr = kw + h * 1024 + w * 256;

    float l = 0.f, s = 0.f;
    #pragma unroll 8
    for (int i = 0; i < 256; ++i) {
        const float kval = h2f(kp[(size_t)i * 2048]);
        const float ex   = __expf(kval * kwr[i] * 0.125f);
        l += ex;
        s += ex * kval;
    }
    __shared__ float sl[256], sv[256];
    sl[t] = l; sv[t] = s;
    __syncthreads();
    if (t < 64) {
        #pragma unroll
        for (int ww = 1; ww < 4; ++ww) {
            l += sl[ww * 64 + e];
            s += sv[ww * 64 + e];
        }
        gk[(size_t)b * DM + h * 64 + e] = s / l;
    }
}

// ---------------------------------------------------------------------------
// v-scale: vq[m][d] = fp16( v16[m][d] * gk[batch][d] ).  (R7 version)
// ---------------------------------------------------------------------------
__global__ __launch_bounds__(256) void vscale_f16(
    const unsigned short* __restrict__ kv, const float* __restrict__ gk,
    unsigned short* __restrict__ vq)
{
    const int m = blockIdx.x;
    const int t = threadIdx.x;
    const int b = m >> 10;
    const ushort4 v4 = *(const ushort4*)(kv + (size_t)m * 2048 + 1024 + t * 4);
    const float4  s4 = *(const float4*)(gk + b * DM + t * 4);
    ushort4 o;
    o.x = f2h(h2f(v4.x) * s4.x);
    o.y = f2h(h2f(v4.y) * s4.y);
    o.z = f2h(h2f(v4.z) * s4.z);
    o.w = f2h(h2f(v4.w) * s4.w);
    *(ushort4*)(vq + (size_t)m * DM + t * 4) = o;
}

// ---------------------------------------------------------------------------
// fp16 MFMA GEMM (R7 structure): 256 thr = 4 waves (2x2), tile 128x128
// (LIN1ACT: 128 x 64 out cols; wn=0 a-half, wn=1 g-half).
// Wave 64x64: acc 64 AGPR; total 128 unified regs = 4 waves/SIMD boundary.
// A: global_load_lds, 2x16KB dbuf, XOR-swizzled rows.
// B: fragment-linear swizzled weights, coalesced direct-to-reg, reg dbuf.
// OUTM: 0 fp16 out, 2 fp32 out + residual.
// ---------------------------------------------------------------------------
template <bool LIN1ACT, int OUTM>
__global__ __launch_bounds__(256, 4) void fgemm(
    const unsigned short* __restrict__ A,
    const unsigned short* __restrict__ Bsw,
    const float* __restrict__ bias,
    const float* __restrict__ residual,
    float* __restrict__ Cf, unsigned short* __restrict__ Cq,
    int K, int lda, int ldc)
{
    __shared__ __align__(16) char lds[32768];   // 2x16KB A stages / 16KB xch

    const int t  = threadIdx.x;
    const int m0 = blockIdx.y * 128;
    const int n0 = blockIdx.x * (LIN1ACT ? 64 : 128);
    const int L  = t & 63, w = t >> 6;
    const int wm = w >> 1, wn = w & 1;
    const int fr = L & 15, q = L >> 4;
    const int KT = K >> 5;

    // A staging: 1024 chunks/stage, 4 per thread; c = t + j*256,
    // row = c>>3 (0..127), chunk-in-row = (c&7)^(row&7).
    const int arow = t >> 3;
    const int ach  = (t & 7) ^ (arow & 7);
    const unsigned short* pA0 = A + (size_t)(m0 + arow) * lda + ach * 8;
    const int ldst0 = t * 16;

    // B fragment-linear base for this wave's 64-col slice.
    const int bcol0 = LIN1ACT ? ((wn ? FFH : 0) + n0) : (n0 + wn * 64);
    const unsigned short* pB = Bsw + (size_t)(bcol0 >> 4) * KT * 512 + L * 8;

    int aoff[4];
    #pragma unroll
    for (int mi = 0; mi < 4; ++mi) {
        const int row = wm * 64 + mi * 16 + fr;
        aoff[mi] = row * 128 + ((q ^ (row & 7)) * 16);
    }

    f32x4 acc[4][4];
    #pragma unroll
    for (int i = 0; i < 4; ++i)
        #pragma unroll
        for (int j = 0; j < 4; ++j) acc[i][j] = (f32x4){0.f, 0.f, 0.f, 0.f};

    // prologue: stage 0 into buf0, B ktile 0 into b0
    #pragma unroll
    for (int j = 0; j < 4; ++j)
        gl2lds16(pA0 + (size_t)j * 32 * lda, lds + ldst0 + j * 4096);
    f16x8 b0[4], b1[4];
    #pragma unroll
    for (int ni = 0; ni < 4; ++ni)
        b0[ni] = *(const f16x8*)(pB + (size_t)ni * KT * 512);
    __syncthreads();

    int p = 0;
    for (int k0 = 0; k0 < K; k0 += 64) {
        const int ktn  = k0 >> 5;
        const int kpre = (k0 + 64 < K) ? k0 + 64 : 0;
        #pragma unroll
        for (int j = 0; j < 4; ++j)
            gl2lds16(pA0 + (size_t)j * 32 * lda + kpre,
                     lds + (p ^ 1) * 16384 + ldst0 + j * 4096);
        #pragma unroll
        for (int ni = 0; ni < 4; ++ni)
            b1[ni] = *(const f16x8*)(pB + ((size_t)ni * KT + ktn + 1) * 512);

        f16x8 af[4];
        #pragma unroll
        for (int mi = 0; mi < 4; ++mi)
            af[mi] = *(const f16x8*)(lds + p * 16384 + aoff[mi]);
        #pragma unroll
        for (int mi = 0; mi < 4; ++mi)
            #pragma unroll
            for (int ni = 0; ni < 4; ++ni)
                acc[mi][ni] = __builtin_amdgcn_mfma_f32_16x16x32_f16(
                    af[mi], b0[ni], acc[mi][ni], 0, 0, 0);

        const int kt2 = (ktn + 2 < KT) ? ktn + 2 : 0;
        #pragma unroll
        for (int ni = 0; ni < 4; ++ni)
            b0[ni] = *(const f16x8*)(pB + ((size_t)ni * KT + kt2) * 512);

        #pragma unroll
        for (int mi = 0; mi < 4; ++mi)
            af[mi] = *(const f16x8*)(lds + p * 16384 + (aoff[mi] ^ 64));
        #pragma unroll
        for (int mi = 0; mi < 4; ++mi)
            #pragma unroll
            for (int ni = 0; ni < 4; ++ni)
                acc[mi][ni] = __builtin_amdgcn_mfma_f32_16x16x32_f16(
                    af[mi], b1[ni], acc[mi][ni], 0, 0, 0);

        __syncthreads();
        p ^= 1;
    }

    if (!LIN1ACT) {
        float bc[4];
        #pragma unroll
        for (int ni = 0; ni < 4; ++ni)
            bc[ni] = bias[n0 + wn * 64 + ni * 16 + fr];
        #pragma unroll
        for (int mi = 0; mi < 4; ++mi)
            #pragma unroll
            for (int ni = 0; ni < 4; ++ni) {
                const int gcol = n0 + wn * 64 + ni * 16 + fr;
                #pragma unroll
                for (int r = 0; r < 4; ++r) {
                    const int grow = m0 + wm * 64 + mi * 16 + q * 4 + r;
                    float v = acc[mi][ni][r] + bc[ni];
                    if (OUTM == 2) {
                        v += residual[(size_t)grow * ldc + gcol];
                        Cf[(size_t)grow * ldc + gcol] = v;
                    } else {
                        Cq[(size_t)grow * ldc + gcol] = f2h(v);
                    }
                }
            }
    } else {
        unsigned short* xch = (unsigned short*)lds;   // [128][64] fp16 = 16KB
        if (wn == 1) {
            #pragma unroll
            for (int mi = 0; mi < 4; ++mi)
                #pragma unroll
                for (int ni = 0; ni < 4; ++ni) {
                    const int col = ni * 16 + fr;
                    const float bg = bias[FFH + n0 + col];
                    #pragma unroll
                    for (int r = 0; r < 4; ++r) {
                        const int row = wm * 64 + mi * 16 + q * 4 + r;
                        xch[row * 64 + col] =
                            f2h(fmaxf(acc[mi][ni][r] + bg, 0.f));
                    }
                }
        }
        __syncthreads();
        if (wn == 0) {
            #pragma unroll
            for (int mi = 0; mi < 4; ++mi)
                #pragma unroll
                for (int ni = 0; ni < 4; ++ni) {
                    const int col = ni * 16 + fr;
                    const float ba = bias[n0 + col];
                    #pragma unroll
                    for (int r = 0; r < 4; ++r) {
                        const int row = wm * 64 + mi * 16 + q * 4 + r;
                        const float a = acc[mi][ni][r] + ba;
                        const float o = a * h2f(xch[row * 64 + col]);
                        Cq[(size_t)(m0 + row) * FFH + n0 + col] = f2h(o);
                    }
                }
        }
    }
}

// ---------------------------------------------------------------------------
extern "C" void kernel_launch(void* const* d_in, const int* in_sizes, int n_in,
                              void* d_out, int out_size, void* d_ws, size_t ws_size,
                              hipStream_t stream)
{
    const float* hidden = (const float*)d_in[0];
    const float* qkv_w  = (const float*)d_in[2];
    const float* qkv_b  = (const float*)d_in[3];
    const float* out_w  = (const float*)d_in[4];
    const float* out_b  = (const float*)d_in[5];
    const float* key_w  = (const float*)d_in[7];
    const float* n1g    = (const float*)d_in[8];
    const float* n1b    = (const float*)d_in[9];
    const float* n2g    = (const float*)d_in[10];
    const float* n2b    = (const float*)d_in[11];
    const float* l1w    = (const float*)d_in[12];
    const float* l1b    = (const float*)d_in[13];
    const float* l2w    = (const float*)d_in[14];
    const float* l2b    = (const float*)d_in[15];
    float* out = (float*)d_out;
    char*  wsb = (char*)d_ws;

    const size_t MB = 1u << 20;
    unsigned short* h16    = (unsigned short*)wsb;               // 16 MB
    unsigned short* kv16   = (unsigned short*)(wsb + 16 * MB);   // 32 MB
    unsigned short* act16  = (unsigned short*)(wsb + 16 * MB);   // overlay
    unsigned short* vq     = (unsigned short*)(wsb + 48 * MB);   // 16 MB
    unsigned short* wkv_sw = (unsigned short*)(wsb + 64 * MB);   // 4 MB
    unsigned short* wo_sw  = (unsigned short*)(wsb + 68 * MB);   // 2 MB
    unsigned short* l1_sw  = (unsigned short*)(wsb + 70 * MB);   // 8 MB
    unsigned short* l2_sw  = (unsigned short*)(wsb + 78 * MB);   // 4 MB
    float*          gk     = (float*)(wsb + 82 * MB);            // 32 KB

    // 0. weights -> fp16 fragment-linear
    wcast_sw<<<4608, 256, 0, stream>>>(
        qkv_w + (size_t)DM * DM, out_w, l1w, l2w,
        wkv_sw, wo_sw, l1_sw, l2_sw);

    // 1. h1 = LN1(hidden) -> fp16
    ln_f16<<<M_TOT, 256, 0, stream>>>(hidden, n1g, n1b, h16);

    // 2. kv16 = fp16( h1 @ Wkv^T + b )  (ldc 2048), 1024 blocks
    fgemm<false, 0><<<dim3(16, 64), 256, 0, stream>>>(
        h16, wkv_sw, qkv_b + DM, nullptr, nullptr, kv16, 1024, 1024, 2048);

    // 3. global_key (single chain-free kernel)
    attn_gk<<<128, 256, 0, stream>>>(kv16, key_w, gk);

    // 4. vq = fp16(v * gk)
    vscale_f16<<<M_TOT, 256, 0, stream>>>(kv16, gk, vq);

    // 5. hidden2 = hidden + vq @ out_w^T + out_b -> d_out, 512 blocks
    fgemm<false, 2><<<dim3(8, 64), 256, 0, stream>>>(
        vq, wo_sw, out_b, hidden, out, nullptr, 1024, 1024, 1024);

    // 6. h2 = LN2(hidden2) -> fp16
    ln_f16<<<M_TOT, 256, 0, stream>>>(out, n2g, n2b, h16);

    // 7. act16 = fp16( (h2@W_a^T+b_a) * relu(h2@W_g^T+b_g) ), 2048 blocks
    fgemm<true, 0><<<dim3(32, 64), 256, 0, stream>>>(
        h16, l1_sw, l1b, nullptr, nullptr, act16, 1024, 1024, 0);

    // 8. out = hidden2 + act @ l2w^T + l2b (in-place residual), 512 blocks
    fgemm<false, 2><<<dim3(8, 64), 256, 0, stream>>>(
        act16, l2_sw, l2b, out, out, nullptr, 2048, 2048, 1024);
}